// Round 5
// baseline (580.885 us; speedup 1.0000x reference)
//
#include <hip/hip_runtime.h>

#define N_NODES 100000
#define N_EDGES 800000
#define DIM 64
#define BN_EPS 1e-5f

// ===========================================================================
// CSR build: count in-degrees, exclusive scan, scatter edges grouped by dst.
// Edge payload packed as int2 {src, bits(w)}.
// ===========================================================================

__global__ __launch_bounds__(256) void k_zero_deg(int* __restrict__ deg) {
    int i = blockIdx.x * blockDim.x + threadIdx.x;
    if (i < N_NODES) deg[i] = 0;
}

__global__ __launch_bounds__(256) void k_count(const int* __restrict__ dst,
                                               int* __restrict__ deg) {
    int e = blockIdx.x * blockDim.x + threadIdx.x;
    if (e < N_EDGES) atomicAdd(&deg[dst[e]], 1);
}

// 98 blocks x 256 threads x 4 elems = 100352 >= N. Per-block exclusive scan.
__global__ __launch_bounds__(256) void k_scan1(const int* __restrict__ deg,
                                               int* __restrict__ row_off,
                                               int* __restrict__ block_sums) {
    __shared__ int sdata[256];
    int tid = threadIdx.x;
    int base = blockIdx.x * 1024 + tid * 4;
    int4 v = make_int4(0, 0, 0, 0);
    if (base < N_NODES) v = *(const int4*)(deg + base);   // N % 4 == 0
    int tsum = v.x + v.y + v.z + v.w;
    sdata[tid] = tsum;
    __syncthreads();
    for (int off = 1; off < 256; off <<= 1) {
        int t = (tid >= off) ? sdata[tid - off] : 0;
        __syncthreads();
        sdata[tid] += t;
        __syncthreads();
    }
    int excl = sdata[tid] - tsum;
    if (base < N_NODES) {
        int4 o;
        o.x = excl;
        o.y = o.x + v.x;
        o.z = o.y + v.y;
        o.w = o.z + v.z;
        *(int4*)(row_off + base) = o;
    }
    if (tid == 255) block_sums[blockIdx.x] = sdata[255];
}

__global__ __launch_bounds__(128) void k_scan2(int* __restrict__ block_sums) {
    __shared__ int sdata[128];
    int tid = threadIdx.x;
    int v = (tid < 98) ? block_sums[tid] : 0;
    sdata[tid] = v;
    __syncthreads();
    for (int off = 1; off < 128; off <<= 1) {
        int t = (tid >= off) ? sdata[tid - off] : 0;
        __syncthreads();
        sdata[tid] += t;
        __syncthreads();
    }
    if (tid < 98) block_sums[tid] = sdata[tid] - v;
}

__global__ __launch_bounds__(256) void k_scan3(const int* __restrict__ deg,
                                               int* __restrict__ row_off,
                                               int* __restrict__ cursor,
                                               float* __restrict__ dinv,
                                               const int* __restrict__ block_sums) {
    int tid = threadIdx.x;
    int base = blockIdx.x * 1024 + tid * 4;
    if (base >= N_NODES) return;
    int p = block_sums[blockIdx.x];
    int4 r = *(const int4*)(row_off + base);
    r.x += p; r.y += p; r.z += p; r.w += p;
    *(int4*)(row_off + base) = r;
    *(int4*)(cursor + base) = r;
    int4 d = *(const int4*)(deg + base);
    float4 di;
    di.x = rsqrtf((float)(d.x + 1));
    di.y = rsqrtf((float)(d.y + 1));
    di.z = rsqrtf((float)(d.z + 1));
    di.w = rsqrtf((float)(d.w + 1));
    *(float4*)(dinv + base) = di;
}

__global__ __launch_bounds__(256) void k_build(const int* __restrict__ ei,
                                               const float* __restrict__ dinv,
                                               int* __restrict__ cursor,
                                               int2* __restrict__ edges) {
    int e = blockIdx.x * blockDim.x + threadIdx.x;
    if (e >= N_EDGES) return;
    int s = ei[e];
    int d = ei[N_EDGES + e];
    int pos = atomicAdd(&cursor[d], 1);
    edges[pos] = make_int2(s, __float_as_int(dinv[s] * dinv[d]));
}

// ===========================================================================
// Tail algebra: W3p = W3 @ pW1, b3p = b3 @ pW1 + pb1  (one block)
// ===========================================================================
__global__ __launch_bounds__(256) void k_fuse_w3(const float* __restrict__ W3,
                                                 const float* __restrict__ b3,
                                                 const float* __restrict__ pW1,
                                                 const float* __restrict__ pb1,
                                                 float* __restrict__ W3p,
                                                 float* __restrict__ b3p) {
    int tid = threadIdx.x;
    int c = tid & 63;
    int kbase = (tid >> 6) * 16;
    for (int k = kbase; k < kbase + 16; ++k) {
        float acc = 0.f;
#pragma unroll 8
        for (int j = 0; j < 64; ++j)
            acc = fmaf(W3[k * 64 + j], pW1[j * 64 + c], acc);
        W3p[k * 64 + c] = acc;
    }
    if (tid < 64) {
        float acc = pb1[c];
#pragma unroll 8
        for (int j = 0; j < 64; ++j)
            acc = fmaf(b3[j], pW1[j * 64 + c], acc);
        b3p[c] = acc;
    }
}

// ===========================================================================
// Aggregation: one 64-lane wave per node, lane = feature column.
// Edge metadata via wave-uniform scalar loads (readfirstlane); 8-deep unroll
// keeps 8 row-gathers in flight. out[n] = dinv[n]^2*x[n] + sum_e w_e*x[src_e]
// ===========================================================================
__global__ __launch_bounds__(256) void k_aggregate(const float* __restrict__ xin,
                                                   const int* __restrict__ row_off,
                                                   const int* __restrict__ deg,
                                                   const int2* __restrict__ edges,
                                                   const float* __restrict__ dinv,
                                                   float* __restrict__ out) {
    int lane = threadIdx.x & 63;
    int node = blockIdx.x * 4 + (threadIdx.x >> 6);   // grid = 25000 exact
    float di = dinv[node];
    float acc = xin[(size_t)node * DIM + lane] * (di * di);
    int beg = __builtin_amdgcn_readfirstlane(row_off[node]);
    int len = __builtin_amdgcn_readfirstlane(deg[node]);
    int end = beg + len;
    int k = beg;
    for (; k + 8 <= end; k += 8) {
        int2 e0 = edges[k + 0];
        int2 e1 = edges[k + 1];
        int2 e2 = edges[k + 2];
        int2 e3 = edges[k + 3];
        int2 e4 = edges[k + 4];
        int2 e5 = edges[k + 5];
        int2 e6 = edges[k + 6];
        int2 e7 = edges[k + 7];
        float v0 = xin[(size_t)e0.x * DIM + lane];
        float v1 = xin[(size_t)e1.x * DIM + lane];
        float v2 = xin[(size_t)e2.x * DIM + lane];
        float v3 = xin[(size_t)e3.x * DIM + lane];
        float v4 = xin[(size_t)e4.x * DIM + lane];
        float v5 = xin[(size_t)e5.x * DIM + lane];
        float v6 = xin[(size_t)e6.x * DIM + lane];
        float v7 = xin[(size_t)e7.x * DIM + lane];
        acc = fmaf(__int_as_float(e0.y), v0, acc);
        acc = fmaf(__int_as_float(e1.y), v1, acc);
        acc = fmaf(__int_as_float(e2.y), v2, acc);
        acc = fmaf(__int_as_float(e3.y), v3, acc);
        acc = fmaf(__int_as_float(e4.y), v4, acc);
        acc = fmaf(__int_as_float(e5.y), v5, acc);
        acc = fmaf(__int_as_float(e6.y), v6, acc);
        acc = fmaf(__int_as_float(e7.y), v7, acc);
    }
    for (; k < end; ++k) {
        int2 e = edges[k];
        acc = fmaf(__int_as_float(e.y), xin[(size_t)e.x * DIM + lane], acc);
    }
    out[(size_t)node * DIM + lane] = acc;
}

// ===========================================================================
// GEMM + epilogue: lane = output column; one W column in 64 VGPRs; x rows
// read via wave-uniform scalar loads (SMEM pipe). 4 independent waves/block,
// 16 rows each, no barriers, no LDS. mode: 0=bias, 1=bias+tanh, 2=bias+BN+ReLU
// ===========================================================================
__global__ __launch_bounds__(256, 4) void k_gemm_ep(const float* __restrict__ xin,
                                                    const float* __restrict__ W,
                                                    const float* __restrict__ bias,
                                                    const float* __restrict__ bng,
                                                    const float* __restrict__ bnb,
                                                    const float* __restrict__ bnm,
                                                    const float* __restrict__ bnv,
                                                    float* __restrict__ out,
                                                    int mode) {
    int lane = threadIdx.x & 63;
    int wv = threadIdx.x >> 6;
    float wcol[64];
#pragma unroll
    for (int k = 0; k < 64; ++k) wcol[k] = W[k * 64 + lane];

    float A = 1.f, B = 0.f;
    if (mode == 2) {
        A = bng[lane] * rsqrtf(bnv[lane] + BN_EPS);
        B = (bias[lane] - bnm[lane]) * A + bnb[lane];
    } else {
        B = bias[lane];
    }

    int row0 = blockIdx.x * 64 + wv * 16;
    for (int r = 0; r < 16; ++r) {
        int row = row0 + r;
        if (row >= N_NODES) return;
        const float* xr = xin + (size_t)row * DIM;
        float a0 = 0.f, a1 = 0.f, a2 = 0.f, a3 = 0.f;
#pragma unroll
        for (int k = 0; k < 64; k += 4) {
            a0 = fmaf(xr[k + 0], wcol[k + 0], a0);
            a1 = fmaf(xr[k + 1], wcol[k + 1], a1);
            a2 = fmaf(xr[k + 2], wcol[k + 2], a2);
            a3 = fmaf(xr[k + 3], wcol[k + 3], a3);
        }
        float h = (a0 + a1) + (a2 + a3);
        float o;
        if (mode == 2)      o = fmaxf(0.f, fmaf(h, A, B));
        else if (mode == 1) o = tanhf(h + B);
        else                o = h + B;
        out[(size_t)row * DIM + lane] = o;
    }
}

// ===========================================================================
extern "C" void kernel_launch(void* const* d_in, const int* in_sizes, int n_in,
                              void* d_out, int out_size, void* d_ws, size_t ws_size,
                              hipStream_t stream) {
    const float* x     = (const float*)d_in[0];
    const int*   ei    = (const int*)d_in[1];
    const float* W1    = (const float*)d_in[2];
    const float* b1    = (const float*)d_in[3];
    const float* W2    = (const float*)d_in[4];
    const float* b2    = (const float*)d_in[5];
    const float* W3    = (const float*)d_in[6];
    const float* b3    = (const float*)d_in[7];
    const float* bn1_g = (const float*)d_in[8];
    const float* bn1_b = (const float*)d_in[9];
    const float* bn1_m = (const float*)d_in[10];
    const float* bn1_v = (const float*)d_in[11];
    const float* bn2_g = (const float*)d_in[12];
    const float* bn2_b = (const float*)d_in[13];
    const float* bn2_m = (const float*)d_in[14];
    const float* bn2_v = (const float*)d_in[15];
    const float* pW1   = (const float*)d_in[16];
    const float* pb1   = (const float*)d_in[17];
    const float* pW2   = (const float*)d_in[18];
    const float* pb2   = (const float*)d_in[19];
    float* out = (float*)d_out;

    char* ws = (char*)d_ws;
    int*   deg      = (int*)ws;                      ws += 100352 * 4;
    int*   row_off  = (int*)ws;                      ws += 100352 * 4;
    int*   cursor   = (int*)ws;                      ws += 100352 * 4;
    int*   bsums    = (int*)ws;                      ws += 128 * 4;
    int2*  edges    = (int2*)ws;                     ws += (size_t)N_EDGES * 8;
    float* dinv     = (float*)ws;                    ws += 100352 * 4;
    float* W3p      = (float*)ws;                    ws += 4096 * 4;
    float* b3p      = (float*)ws;                    ws += 64 * 4;
    float* bufA     = (float*)ws;                    ws += (size_t)N_NODES * DIM * 4;
    float* bufB     = (float*)ws;

    const int blk = 256;
    int gN    = (N_NODES + blk - 1) / blk;       // 391
    int gE    = (N_EDGES + blk - 1) / blk;       // 3125
    int gScan = 98;
    int gAgg  = N_NODES / 4;                     // 25000 (exact)
    int gGemm = (N_NODES + 63) / 64;             // 1563

    // ---- CSR build (once, reused by all 3 layers) ----
    k_zero_deg<<<gN, blk, 0, stream>>>(deg);
    k_count<<<gE, blk, 0, stream>>>(ei + N_EDGES, deg);
    k_scan1<<<gScan, blk, 0, stream>>>(deg, row_off, bsums);
    k_scan2<<<1, 128, 0, stream>>>(bsums);
    k_scan3<<<gScan, blk, 0, stream>>>(deg, row_off, cursor, dinv, bsums);
    k_build<<<gE, blk, 0, stream>>>(ei, dinv, cursor, edges);
    k_fuse_w3<<<1, blk, 0, stream>>>(W3, b3, pW1, pb1, W3p, b3p);

    // ---- layer 1 ----
    k_aggregate<<<gAgg, blk, 0, stream>>>(x, row_off, deg, edges, dinv, bufA);
    k_gemm_ep<<<gGemm, blk, 0, stream>>>(bufA, W1, b1, bn1_g, bn1_b, bn1_m, bn1_v, bufB, 2);

    // ---- layer 2 ----
    k_aggregate<<<gAgg, blk, 0, stream>>>(bufB, row_off, deg, edges, dinv, bufA);
    k_gemm_ep<<<gGemm, blk, 0, stream>>>(bufA, W2, b2, bn2_g, bn2_b, bn2_m, bn2_v, bufB, 2);

    // ---- layer 3 + fused predictor ----
    k_aggregate<<<gAgg, blk, 0, stream>>>(bufB, row_off, deg, edges, dinv, bufA);
    k_gemm_ep<<<gGemm, blk, 0, stream>>>(bufA, W3p, b3p, nullptr, nullptr, nullptr, nullptr, bufB, 1);
    k_gemm_ep<<<gGemm, blk, 0, stream>>>(bufB, pW2, pb2, nullptr, nullptr, nullptr, nullptr, out, 0);
}

// Round 6
// 408.719 us; speedup vs baseline: 1.4212x; 1.4212x over previous
//
#include <hip/hip_runtime.h>

#define N_NODES 100000
#define N_EDGES 800000
#define DIM 64
#define BN_EPS 1e-5f

// ===========================================================================
// CSR build: count in-degrees, exclusive scan, scatter edges grouped by dst.
// Edge payload packed as int2 {src, bits(w)}.
// ===========================================================================

__global__ __launch_bounds__(256) void k_zero_deg(int* __restrict__ deg) {
    int i = blockIdx.x * blockDim.x + threadIdx.x;
    if (i < N_NODES) deg[i] = 0;
}

__global__ __launch_bounds__(256) void k_count(const int* __restrict__ dst,
                                               int* __restrict__ deg) {
    int e = blockIdx.x * blockDim.x + threadIdx.x;
    if (e < N_EDGES) atomicAdd(&deg[dst[e]], 1);
}

// 98 blocks x 256 threads x 4 elems = 100352 >= N. Per-block exclusive scan.
__global__ __launch_bounds__(256) void k_scan1(const int* __restrict__ deg,
                                               int* __restrict__ row_off,
                                               int* __restrict__ block_sums) {
    __shared__ int sdata[256];
    int tid = threadIdx.x;
    int base = blockIdx.x * 1024 + tid * 4;
    int4 v = make_int4(0, 0, 0, 0);
    if (base < N_NODES) v = *(const int4*)(deg + base);   // N % 4 == 0
    int tsum = v.x + v.y + v.z + v.w;
    sdata[tid] = tsum;
    __syncthreads();
    for (int off = 1; off < 256; off <<= 1) {
        int t = (tid >= off) ? sdata[tid - off] : 0;
        __syncthreads();
        sdata[tid] += t;
        __syncthreads();
    }
    int excl = sdata[tid] - tsum;
    if (base < N_NODES) {
        int4 o;
        o.x = excl;
        o.y = o.x + v.x;
        o.z = o.y + v.y;
        o.w = o.z + v.z;
        *(int4*)(row_off + base) = o;
    }
    if (tid == 255) block_sums[blockIdx.x] = sdata[255];
}

__global__ __launch_bounds__(128) void k_scan2(int* __restrict__ block_sums) {
    __shared__ int sdata[128];
    int tid = threadIdx.x;
    int v = (tid < 98) ? block_sums[tid] : 0;
    sdata[tid] = v;
    __syncthreads();
    for (int off = 1; off < 128; off <<= 1) {
        int t = (tid >= off) ? sdata[tid - off] : 0;
        __syncthreads();
        sdata[tid] += t;
        __syncthreads();
    }
    if (tid < 98) block_sums[tid] = sdata[tid] - v;
}

__global__ __launch_bounds__(256) void k_scan3(const int* __restrict__ deg,
                                               int* __restrict__ row_off,
                                               int* __restrict__ cursor,
                                               float* __restrict__ dinv,
                                               const int* __restrict__ block_sums) {
    int tid = threadIdx.x;
    int base = blockIdx.x * 1024 + tid * 4;
    if (base >= N_NODES) return;
    int p = block_sums[blockIdx.x];
    int4 r = *(const int4*)(row_off + base);
    r.x += p; r.y += p; r.z += p; r.w += p;
    *(int4*)(row_off + base) = r;
    *(int4*)(cursor + base) = r;
    int4 d = *(const int4*)(deg + base);
    float4 di;
    di.x = rsqrtf((float)(d.x + 1));
    di.y = rsqrtf((float)(d.y + 1));
    di.z = rsqrtf((float)(d.z + 1));
    di.w = rsqrtf((float)(d.w + 1));
    *(float4*)(dinv + base) = di;
}

__global__ __launch_bounds__(256) void k_build(const int* __restrict__ ei,
                                               const float* __restrict__ dinv,
                                               int* __restrict__ cursor,
                                               int2* __restrict__ edges) {
    int e = blockIdx.x * blockDim.x + threadIdx.x;
    if (e >= N_EDGES) return;
    int s = ei[e];
    int d = ei[N_EDGES + e];
    int pos = atomicAdd(&cursor[d], 1);
    edges[pos] = make_int2(s, __float_as_int(dinv[s] * dinv[d]));
}

// ===========================================================================
// Tail algebra: W3p = W3 @ pW1, b3p = b3 @ pW1 + pb1  (one block)
// ===========================================================================
__global__ __launch_bounds__(256) void k_fuse_w3(const float* __restrict__ W3,
                                                 const float* __restrict__ b3,
                                                 const float* __restrict__ pW1,
                                                 const float* __restrict__ pb1,
                                                 float* __restrict__ W3p,
                                                 float* __restrict__ b3p) {
    int tid = threadIdx.x;
    int c = tid & 63;
    int kbase = (tid >> 6) * 16;
    for (int k = kbase; k < kbase + 16; ++k) {
        float acc = 0.f;
#pragma unroll 8
        for (int j = 0; j < 64; ++j)
            acc = fmaf(W3[k * 64 + j], pW1[j * 64 + c], acc);
        W3p[k * 64 + c] = acc;
    }
    if (tid < 64) {
        float acc = pb1[c];
#pragma unroll 8
        for (int j = 0; j < 64; ++j)
            acc = fmaf(b3[j], pW1[j * 64 + c], acc);
        b3p[c] = acc;
    }
}

// ===========================================================================
// Aggregation: one 64-lane wave per node, lane = feature column.
// Edge metadata via wave-uniform scalar loads (readfirstlane); 8-deep unroll
// keeps 8 row-gathers in flight. out[n] = dinv[n]^2*x[n] + sum_e w_e*x[src_e]
// ===========================================================================
__global__ __launch_bounds__(256) void k_aggregate(const float* __restrict__ xin,
                                                   const int* __restrict__ row_off,
                                                   const int* __restrict__ deg,
                                                   const int2* __restrict__ edges,
                                                   const float* __restrict__ dinv,
                                                   float* __restrict__ out) {
    int lane = threadIdx.x & 63;
    int node = blockIdx.x * 4 + (threadIdx.x >> 6);   // grid = 25000 exact
    float di = dinv[node];
    float acc = xin[(size_t)node * DIM + lane] * (di * di);
    int beg = __builtin_amdgcn_readfirstlane(row_off[node]);
    int len = __builtin_amdgcn_readfirstlane(deg[node]);
    int end = beg + len;
    int k = beg;
    for (; k + 8 <= end; k += 8) {
        int2 e0 = edges[k + 0];
        int2 e1 = edges[k + 1];
        int2 e2 = edges[k + 2];
        int2 e3 = edges[k + 3];
        int2 e4 = edges[k + 4];
        int2 e5 = edges[k + 5];
        int2 e6 = edges[k + 6];
        int2 e7 = edges[k + 7];
        float v0 = xin[(size_t)e0.x * DIM + lane];
        float v1 = xin[(size_t)e1.x * DIM + lane];
        float v2 = xin[(size_t)e2.x * DIM + lane];
        float v3 = xin[(size_t)e3.x * DIM + lane];
        float v4 = xin[(size_t)e4.x * DIM + lane];
        float v5 = xin[(size_t)e5.x * DIM + lane];
        float v6 = xin[(size_t)e6.x * DIM + lane];
        float v7 = xin[(size_t)e7.x * DIM + lane];
        acc = fmaf(__int_as_float(e0.y), v0, acc);
        acc = fmaf(__int_as_float(e1.y), v1, acc);
        acc = fmaf(__int_as_float(e2.y), v2, acc);
        acc = fmaf(__int_as_float(e3.y), v3, acc);
        acc = fmaf(__int_as_float(e4.y), v4, acc);
        acc = fmaf(__int_as_float(e5.y), v5, acc);
        acc = fmaf(__int_as_float(e6.y), v6, acc);
        acc = fmaf(__int_as_float(e7.y), v7, acc);
    }
    for (; k < end; ++k) {
        int2 e = edges[k];
        acc = fmaf(__int_as_float(e.y), xin[(size_t)e.x * DIM + lane], acc);
    }
    out[(size_t)node * DIM + lane] = acc;
}

// ===========================================================================
// Register-tiled GEMM: block = 64 rows x 64 cols, thread = 4x4 outputs.
// X tile and W both in LDS, row-major; K unrolled x4 outer-product style:
// per 4-k-step each thread does 8 ds_read_b128 + 64 FMAs (VALU-bound).
// mode: 0 = bias, 2 = bias + BN + ReLU
// ===========================================================================
__global__ __launch_bounds__(256) void k_gemm_tile(const float* __restrict__ xin,
                                                   const float* __restrict__ W,
                                                   const float* __restrict__ bias,
                                                   const float* __restrict__ bng,
                                                   const float* __restrict__ bnb,
                                                   const float* __restrict__ bnm,
                                                   const float* __restrict__ bnv,
                                                   float* __restrict__ out,
                                                   int mode) {
    __shared__ float sW[4096];
    __shared__ float sX[4096];
    int tid = threadIdx.x;
    int row0 = blockIdx.x * 64;

    for (int i = tid; i < 1024; i += 256)
        ((float4*)sW)[i] = ((const float4*)W)[i];
    {
        int r = tid >> 2;          // 0..63
        int q = tid & 3;
        int row = row0 + r;
        float4* dst = (float4*)(sX + r * 64);
        if (row < N_NODES) {
            const float4* src = (const float4*)(xin + (size_t)row * DIM);
#pragma unroll
            for (int m = 0; m < 4; ++m) dst[q + m * 4] = src[q + m * 4];
        } else {
            float4 z = make_float4(0.f, 0.f, 0.f, 0.f);
#pragma unroll
            for (int m = 0; m < 4; ++m) dst[q + m * 4] = z;
        }
    }
    __syncthreads();

    int cq = tid & 15, rq = tid >> 4;
    int c0 = cq * 4, r0 = rq * 4;
    float acc[4][4];
#pragma unroll
    for (int i = 0; i < 4; ++i)
#pragma unroll
        for (int j = 0; j < 4; ++j) acc[i][j] = 0.f;

#pragma unroll 4
    for (int k4 = 0; k4 < 16; ++k4) {
        float4 a0 = *(const float4*)&sX[(r0 + 0) * 64 + k4 * 4];
        float4 a1 = *(const float4*)&sX[(r0 + 1) * 64 + k4 * 4];
        float4 a2 = *(const float4*)&sX[(r0 + 2) * 64 + k4 * 4];
        float4 a3 = *(const float4*)&sX[(r0 + 3) * 64 + k4 * 4];
        float4 b0 = *(const float4*)&sW[(k4 * 4 + 0) * 64 + c0];
        float4 b1 = *(const float4*)&sW[(k4 * 4 + 1) * 64 + c0];
        float4 b2 = *(const float4*)&sW[(k4 * 4 + 2) * 64 + c0];
        float4 b3 = *(const float4*)&sW[(k4 * 4 + 3) * 64 + c0];
        const float* ap[4] = {&a0.x, &a1.x, &a2.x, &a3.x};
#pragma unroll
        for (int i = 0; i < 4; ++i) {
            float x0 = ap[i][0], x1 = ap[i][1], x2 = ap[i][2], x3 = ap[i][3];
            acc[i][0] = fmaf(x0, b0.x, acc[i][0]);
            acc[i][1] = fmaf(x0, b0.y, acc[i][1]);
            acc[i][2] = fmaf(x0, b0.z, acc[i][2]);
            acc[i][3] = fmaf(x0, b0.w, acc[i][3]);
            acc[i][0] = fmaf(x1, b1.x, acc[i][0]);
            acc[i][1] = fmaf(x1, b1.y, acc[i][1]);
            acc[i][2] = fmaf(x1, b1.z, acc[i][2]);
            acc[i][3] = fmaf(x1, b1.w, acc[i][3]);
            acc[i][0] = fmaf(x2, b2.x, acc[i][0]);
            acc[i][1] = fmaf(x2, b2.y, acc[i][1]);
            acc[i][2] = fmaf(x2, b2.z, acc[i][2]);
            acc[i][3] = fmaf(x2, b2.w, acc[i][3]);
            acc[i][0] = fmaf(x3, b3.x, acc[i][0]);
            acc[i][1] = fmaf(x3, b3.y, acc[i][1]);
            acc[i][2] = fmaf(x3, b3.z, acc[i][2]);
            acc[i][3] = fmaf(x3, b3.w, acc[i][3]);
        }
    }

    float4 bv = *(const float4*)&bias[c0];
    if (mode == 2) {
        float4 g = *(const float4*)&bng[c0];
        float4 bb = *(const float4*)&bnb[c0];
        float4 m = *(const float4*)&bnm[c0];
        float4 vv = *(const float4*)&bnv[c0];
        float A0 = g.x * rsqrtf(vv.x + BN_EPS);
        float A1 = g.y * rsqrtf(vv.y + BN_EPS);
        float A2 = g.z * rsqrtf(vv.z + BN_EPS);
        float A3 = g.w * rsqrtf(vv.w + BN_EPS);
        float B0 = (bv.x - m.x) * A0 + bb.x;
        float B1 = (bv.y - m.y) * A1 + bb.y;
        float B2 = (bv.z - m.z) * A2 + bb.z;
        float B3 = (bv.w - m.w) * A3 + bb.w;
#pragma unroll
        for (int i = 0; i < 4; ++i) {
            int row = row0 + r0 + i;
            if (row >= N_NODES) break;
            float4 o;
            o.x = fmaxf(0.f, fmaf(acc[i][0], A0, B0));
            o.y = fmaxf(0.f, fmaf(acc[i][1], A1, B1));
            o.z = fmaxf(0.f, fmaf(acc[i][2], A2, B2));
            o.w = fmaxf(0.f, fmaf(acc[i][3], A3, B3));
            *(float4*)(out + (size_t)row * DIM + c0) = o;
        }
    } else {
#pragma unroll
        for (int i = 0; i < 4; ++i) {
            int row = row0 + r0 + i;
            if (row >= N_NODES) break;
            float4 o;
            o.x = acc[i][0] + bv.x;
            o.y = acc[i][1] + bv.y;
            o.z = acc[i][2] + bv.z;
            o.w = acc[i][3] + bv.w;
            *(float4*)(out + (size_t)row * DIM + c0) = o;
        }
    }
}

// ===========================================================================
// Tail: out = tanh(x @ W3p + b3p) @ pW2 + pb2, one kernel, tanh tile kept
// in LDS between the two register-tiled GEMMs.
// ===========================================================================
__global__ __launch_bounds__(256) void k_tail(const float* __restrict__ xin,
                                              const float* __restrict__ W3p,
                                              const float* __restrict__ b3p,
                                              const float* __restrict__ pW2,
                                              const float* __restrict__ pb2,
                                              float* __restrict__ out) {
    __shared__ float sW1[4096];
    __shared__ float sW2[4096];
    __shared__ float sX[4096];
    int tid = threadIdx.x;
    int row0 = blockIdx.x * 64;

    for (int i = tid; i < 1024; i += 256) {
        ((float4*)sW1)[i] = ((const float4*)W3p)[i];
        ((float4*)sW2)[i] = ((const float4*)pW2)[i];
    }
    {
        int r = tid >> 2;
        int q = tid & 3;
        int row = row0 + r;
        float4* dst = (float4*)(sX + r * 64);
        if (row < N_NODES) {
            const float4* src = (const float4*)(xin + (size_t)row * DIM);
#pragma unroll
            for (int m = 0; m < 4; ++m) dst[q + m * 4] = src[q + m * 4];
        } else {
            float4 z = make_float4(0.f, 0.f, 0.f, 0.f);
#pragma unroll
            for (int m = 0; m < 4; ++m) dst[q + m * 4] = z;
        }
    }
    __syncthreads();

    int cq = tid & 15, rq = tid >> 4;
    int c0 = cq * 4, r0 = rq * 4;
    float acc[4][4];

    // ---- GEMM 1: sX @ sW1 ----
#pragma unroll
    for (int i = 0; i < 4; ++i)
#pragma unroll
        for (int j = 0; j < 4; ++j) acc[i][j] = 0.f;
#pragma unroll 4
    for (int k4 = 0; k4 < 16; ++k4) {
        float4 a0 = *(const float4*)&sX[(r0 + 0) * 64 + k4 * 4];
        float4 a1 = *(const float4*)&sX[(r0 + 1) * 64 + k4 * 4];
        float4 a2 = *(const float4*)&sX[(r0 + 2) * 64 + k4 * 4];
        float4 a3 = *(const float4*)&sX[(r0 + 3) * 64 + k4 * 4];
        float4 b0 = *(const float4*)&sW1[(k4 * 4 + 0) * 64 + c0];
        float4 b1 = *(const float4*)&sW1[(k4 * 4 + 1) * 64 + c0];
        float4 b2 = *(const float4*)&sW1[(k4 * 4 + 2) * 64 + c0];
        float4 b3 = *(const float4*)&sW1[(k4 * 4 + 3) * 64 + c0];
        const float* ap[4] = {&a0.x, &a1.x, &a2.x, &a3.x};
#pragma unroll
        for (int i = 0; i < 4; ++i) {
            float x0 = ap[i][0], x1 = ap[i][1], x2 = ap[i][2], x3 = ap[i][3];
            acc[i][0] = fmaf(x0, b0.x, acc[i][0]);
            acc[i][1] = fmaf(x0, b0.y, acc[i][1]);
            acc[i][2] = fmaf(x0, b0.z, acc[i][2]);
            acc[i][3] = fmaf(x0, b0.w, acc[i][3]);
            acc[i][0] = fmaf(x1, b1.x, acc[i][0]);
            acc[i][1] = fmaf(x1, b1.y, acc[i][1]);
            acc[i][2] = fmaf(x1, b1.z, acc[i][2]);
            acc[i][3] = fmaf(x1, b1.w, acc[i][3]);
            acc[i][0] = fmaf(x2, b2.x, acc[i][0]);
            acc[i][1] = fmaf(x2, b2.y, acc[i][1]);
            acc[i][2] = fmaf(x2, b2.z, acc[i][2]);
            acc[i][3] = fmaf(x2, b2.w, acc[i][3]);
            acc[i][0] = fmaf(x3, b3.x, acc[i][0]);
            acc[i][1] = fmaf(x3, b3.y, acc[i][1]);
            acc[i][2] = fmaf(x3, b3.z, acc[i][2]);
            acc[i][3] = fmaf(x3, b3.w, acc[i][3]);
        }
    }
    __syncthreads();   // all reads of sX done

    // tanh + bias, write H back into sX
    {
        float4 bv = *(const float4*)&b3p[c0];
#pragma unroll
        for (int i = 0; i < 4; ++i) {
            float4 h;
            h.x = tanhf(acc[i][0] + bv.x);
            h.y = tanhf(acc[i][1] + bv.y);
            h.z = tanhf(acc[i][2] + bv.z);
            h.w = tanhf(acc[i][3] + bv.w);
            *(float4*)&sX[(r0 + i) * 64 + c0] = h;
        }
    }
    __syncthreads();

    // ---- GEMM 2: sX @ sW2 ----
#pragma unroll
    for (int i = 0; i < 4; ++i)
#pragma unroll
        for (int j = 0; j < 4; ++j) acc[i][j] = 0.f;
#pragma unroll 4
    for (int k4 = 0; k4 < 16; ++k4) {
        float4 a0 = *(const float4*)&sX[(r0 + 0) * 64 + k4 * 4];
        float4 a1 = *(const float4*)&sX[(r0 + 1) * 64 + k4 * 4];
        float4 a2 = *(const float4*)&sX[(r0 + 2) * 64 + k4 * 4];
        float4 a3 = *(const float4*)&sX[(r0 + 3) * 64 + k4 * 4];
        float4 b0 = *(const float4*)&sW2[(k4 * 4 + 0) * 64 + c0];
        float4 b1 = *(const float4*)&sW2[(k4 * 4 + 1) * 64 + c0];
        float4 b2 = *(const float4*)&sW2[(k4 * 4 + 2) * 64 + c0];
        float4 b3 = *(const float4*)&sW2[(k4 * 4 + 3) * 64 + c0];
        const float* ap[4] = {&a0.x, &a1.x, &a2.x, &a3.x};
#pragma unroll
        for (int i = 0; i < 4; ++i) {
            float x0 = ap[i][0], x1 = ap[i][1], x2 = ap[i][2], x3 = ap[i][3];
            acc[i][0] = fmaf(x0, b0.x, acc[i][0]);
            acc[i][1] = fmaf(x0, b0.y, acc[i][1]);
            acc[i][2] = fmaf(x0, b0.z, acc[i][2]);
            acc[i][3] = fmaf(x0, b0.w, acc[i][3]);
            acc[i][0] = fmaf(x1, b1.x, acc[i][0]);
            acc[i][1] = fmaf(x1, b1.y, acc[i][1]);
            acc[i][2] = fmaf(x1, b1.z, acc[i][2]);
            acc[i][3] = fmaf(x1, b1.w, acc[i][3]);
            acc[i][0] = fmaf(x2, b2.x, acc[i][0]);
            acc[i][1] = fmaf(x2, b2.y, acc[i][1]);
            acc[i][2] = fmaf(x2, b2.z, acc[i][2]);
            acc[i][3] = fmaf(x2, b2.w, acc[i][3]);
            acc[i][0] = fmaf(x3, b3.x, acc[i][0]);
            acc[i][1] = fmaf(x3, b3.y, acc[i][1]);
            acc[i][2] = fmaf(x3, b3.z, acc[i][2]);
            acc[i][3] = fmaf(x3, b3.w, acc[i][3]);
        }
    }

    float4 bv = *(const float4*)&pb2[c0];
#pragma unroll
    for (int i = 0; i < 4; ++i) {
        int row = row0 + r0 + i;
        if (row >= N_NODES) break;
        float4 o;
        o.x = acc[i][0] + bv.x;
        o.y = acc[i][1] + bv.y;
        o.z = acc[i][2] + bv.z;
        o.w = acc[i][3] + bv.w;
        *(float4*)(out + (size_t)row * DIM + c0) = o;
    }
}

// ===========================================================================
extern "C" void kernel_launch(void* const* d_in, const int* in_sizes, int n_in,
                              void* d_out, int out_size, void* d_ws, size_t ws_size,
                              hipStream_t stream) {
    const float* x     = (const float*)d_in[0];
    const int*   ei    = (const int*)d_in[1];
    const float* W1    = (const float*)d_in[2];
    const float* b1    = (const float*)d_in[3];
    const float* W2    = (const float*)d_in[4];
    const float* b2    = (const float*)d_in[5];
    const float* W3    = (const float*)d_in[6];
    const float* b3    = (const float*)d_in[7];
    const float* bn1_g = (const float*)d_in[8];
    const float* bn1_b = (const float*)d_in[9];
    const float* bn1_m = (const float*)d_in[10];
    const float* bn1_v = (const float*)d_in[11];
    const float* bn2_g = (const float*)d_in[12];
    const float* bn2_b = (const float*)d_in[13];
    const float* bn2_m = (const float*)d_in[14];
    const float* bn2_v = (const float*)d_in[15];
    const float* pW1   = (const float*)d_in[16];
    const float* pb1   = (const float*)d_in[17];
    const float* pW2   = (const float*)d_in[18];
    const float* pb2   = (const float*)d_in[19];
    float* out = (float*)d_out;

    char* ws = (char*)d_ws;
    int*   deg      = (int*)ws;                      ws += 100352 * 4;
    int*   row_off  = (int*)ws;                      ws += 100352 * 4;
    int*   cursor   = (int*)ws;                      ws += 100352 * 4;
    int*   bsums    = (int*)ws;                      ws += 128 * 4;
    int2*  edges    = (int2*)ws;                     ws += (size_t)N_EDGES * 8;
    float* dinv     = (float*)ws;                    ws += 100352 * 4;
    float* W3p      = (float*)ws;                    ws += 4096 * 4;
    float* b3p      = (float*)ws;                    ws += 64 * 4;
    float* bufA     = (float*)ws;                    ws += (size_t)N_NODES * DIM * 4;
    float* bufB     = (float*)ws;

    const int blk = 256;
    int gN    = (N_NODES + blk - 1) / blk;       // 391
    int gE    = (N_EDGES + blk - 1) / blk;       // 3125
    int gScan = 98;
    int gAgg  = N_NODES / 4;                     // 25000 (exact)
    int gGemm = (N_NODES + 63) / 64;             // 1563

    // ---- CSR build (once, reused by all 3 layers) ----
    k_zero_deg<<<gN, blk, 0, stream>>>(deg);
    k_count<<<gE, blk, 0, stream>>>(ei + N_EDGES, deg);
    k_scan1<<<gScan, blk, 0, stream>>>(deg, row_off, bsums);
    k_scan2<<<1, 128, 0, stream>>>(bsums);
    k_scan3<<<gScan, blk, 0, stream>>>(deg, row_off, cursor, dinv, bsums);
    k_build<<<gE, blk, 0, stream>>>(ei, dinv, cursor, edges);
    k_fuse_w3<<<1, blk, 0, stream>>>(W3, b3, pW1, pb1, W3p, b3p);

    // ---- layer 1 ----
    k_aggregate<<<gAgg, blk, 0, stream>>>(x, row_off, deg, edges, dinv, bufA);
    k_gemm_tile<<<gGemm, blk, 0, stream>>>(bufA, W1, b1, bn1_g, bn1_b, bn1_m, bn1_v, bufB, 2);

    // ---- layer 2 ----
    k_aggregate<<<gAgg, blk, 0, stream>>>(bufB, row_off, deg, edges, dinv, bufA);
    k_gemm_tile<<<gGemm, blk, 0, stream>>>(bufA, W2, b2, bn2_g, bn2_b, bn2_m, bn2_v, bufB, 2);

    // ---- layer 3 + fused predictor ----
    k_aggregate<<<gAgg, blk, 0, stream>>>(bufB, row_off, deg, edges, dinv, bufA);
    k_tail<<<gGemm, blk, 0, stream>>>(bufA, W3p, b3p, pW2, pb2, out);
}